// Round 10
// baseline (221.973 us; speedup 1.0000x reference)
//
#include <hip/hip_runtime.h>
#include <math.h>

// Causal MHA forward, B=2 H=16 S=2048 D=64, fp32 in/out, bf16 MFMA compute.
// Round 15: BARRIER-FREE fa. Revert round-14 K-fusion (net negative). Keep
// round-12 prep (K->bf16 Kb, V->bf16-transposed Vt, both L2-resident).
//  - fa has NO LDS and NO __syncthreads: each wave reads its K/V MFMA
//    fragments directly from Kb/Vt (16 x 16B loads per 64-col tile),
//    software-pipelined ONE TILE AHEAD into an alternate register set
//    (unroll-2, static parity). Full tile body covers L2 latency; waves
//    slip freely (no convoy); 4 waves/block walk the same 16KB tile -> L1
//    serves the cross-wave re-read.
//  - Flat 33-tile sequence per wave (phase A tr=pr kt=0..pr, phase B
//    tr=31-pr kt=0..31-pr) -> uniform length for every block; diag mask and
//    phase epilogue both trigger at kt==tr.
//  - Keeps verified compute: swapped QK^T, in-register P transpose
//    (cvt_pk+permlane), MFMA row-sum (lacc), fixed-max softmax, s_setprio.

#define S_LEN   2048
#define D_HEAD  64
#define SCALE_L2E 0.18033688011112042f   // (1/sqrt(D)) * log2(e)
#define FIXM    8.0f                     // fixed softmax offset (exponent-safe)

using bf16x8 = __attribute__((ext_vector_type(8))) short;
using f32x4  = __attribute__((ext_vector_type(4))) float;
using uint4v = __attribute__((ext_vector_type(4))) unsigned int;

__device__ __forceinline__ unsigned int rnd_bf(float f) {
  return __float_as_uint(f) + 0x8000u;
}
__device__ __forceinline__ unsigned short f2bf(float f) {
  return (unsigned short)(rnd_bf(f) >> 16);
}

// pack two f32 -> one dword of 2 x bf16 (lo = first arg)
__device__ __forceinline__ unsigned int cvtpk_bf16(float lo, float hi) {
  unsigned int r;
  asm("v_cvt_pk_bf16_f32 %0, %1, %2" : "=v"(r) : "v"(lo), "v"(hi));
  return r;
}
// a' = [a.lo32, b.lo32]; b' = [a.hi32, b.hi32]
__device__ __forceinline__ void swap32(unsigned int& a, unsigned int& b) {
  asm("v_permlane32_swap_b32 %0, %1" : "+v"(a), "+v"(b));
}
// rows = 16-lane groups: a' = [a.r0, b.r0, a.r2, b.r2]; b' = [a.r1, b.r1, a.r3, b.r3]
__device__ __forceinline__ void swap16(unsigned int& a, unsigned int& b) {
  asm("v_permlane16_swap_b32 %0, %1" : "+v"(a), "+v"(b));
}

// DPP cross-lane 16-wide sum (fa_fb epilogue only)
template <int CTRL>
__device__ __forceinline__ float dppf(float x) {
  return __builtin_bit_cast(float,
      __builtin_amdgcn_update_dpp(0, __builtin_bit_cast(int, x), CTRL, 0xF, 0xF, false));
}
__device__ __forceinline__ float rowsum16(float x) {
  x += dppf<0xB1>(x);
  x += dppf<0x4E>(x);
  x += dppf<0x124>(x);
  x += dppf<0x128>(x);
  return x;
}

// ---------------- pre-pass: K -> bf16 [bh][s][d]; V -> bf16 transposed [bh][d][s]
__global__ __launch_bounds__(256, 4)
void prep(const float* __restrict__ Kg, const float* __restrict__ Vg,
          unsigned short* __restrict__ Kb, unsigned short* __restrict__ Vt)
{
  __shared__ __align__(16) unsigned short Lt[64][72];
  const int j = blockIdx.x, t = threadIdx.x;
  const int bh = j >> 4, seg = j & 15;
  const size_t base = (size_t)bh * (S_LEN * D_HEAD) + (size_t)seg * 128 * D_HEAD;
#pragma unroll
  for (int i = 0; i < 8; ++i) {
    const size_t idx = base + i * 1024 + t * 4;
    const f32x4 v = *(const f32x4*)(Kg + idx);
    uint2 pk;
    pk.x = (rnd_bf(v[1]) & 0xFFFF0000u) | (rnd_bf(v[0]) >> 16);
    pk.y = (rnd_bf(v[3]) & 0xFFFF0000u) | (rnd_bf(v[2]) >> 16);
    *(uint2*)(Kb + idx) = pk;
  }
  for (int h = 0; h < 2; ++h) {
    const int s0 = seg * 128 + h * 64;
    __syncthreads();
#pragma unroll
    for (int pp = 0; pp < 4; ++pp) {
      const int r = t >> 2;
      const int d0 = (t & 3) * 4 + pp * 16;
      const f32x4 v = *(const f32x4*)(Vg + (size_t)bh * (S_LEN * D_HEAD)
                                         + (size_t)(s0 + r) * D_HEAD + d0);
#pragma unroll
      for (int e = 0; e < 4; ++e) Lt[d0 + e][r] = f2bf(v[e]);
    }
    __syncthreads();
#pragma unroll
    for (int q = 0; q < 2; ++q) {
      const int d = t >> 2, ch = (t & 3) + 4 * q;
      *(uint4*)(Vt + (size_t)(bh * 64 + d) * S_LEN + s0 + ch * 8) =
          *(const uint4*)&Lt[d][ch * 8];
    }
  }
}

// ---------------- main attention: barrier-free, LDS-free, 1-tile-ahead pipeline
__global__ __launch_bounds__(256, 2)
void fa(const float* __restrict__ Qg, const unsigned short* __restrict__ Kb,
        const unsigned short* __restrict__ Vt, float* __restrict__ Og)
{
  const int id = blockIdx.x;            // 512 blocks
  const int bh = id & 31;               // id%8 == bh%8 -> head-local XCD L2 reuse
  const int pr = id >> 5;               // tile-row pair 0..15

  const int t    = threadIdx.x;         // 0..255
  const int w    = t >> 6;
  const int lane = t & 63;
  const int c    = lane & 15;
  const int quad = lane >> 4;

  const float* __restrict__ Qb = Qg + (size_t)bh * (S_LEN * D_HEAD);
  const unsigned short* __restrict__ Kbb = Kb + (size_t)bh * (S_LEN * D_HEAD);
  const unsigned short* __restrict__ Vtb = Vt + (size_t)bh * (D_HEAD * S_LEN);
  float* __restrict__ Ob = Og + (size_t)bh * (S_LEN * D_HEAD);

  const int trA = pr, trB = 31 - pr;    // phase A: kt=0..trA; phase B: 0..trB
  const int rowA = trA * 64 + w * 16, rowB = trB * 64 + w * 16;

  // ---- per-lane invariant fragment offsets (shorts)
  int kOff[4][2], vOff[4][2];
#pragma unroll
  for (int ci = 0; ci < 4; ++ci)
#pragma unroll
    for (int h = 0; h < 2; ++h) {
      kOff[ci][h] = (ci * 16 + c) * 64   + h * 32 + quad * 8;
      vOff[ci][h] = (ci * 16 + c) * 2048 + h * 32 + quad * 8;
    }

  // ones B-fragment for the row-sum MFMA (bf16 1.0)
  bf16x8 ones;
#pragma unroll
  for (int j = 0; j < 8; ++j) ones[j] = (short)0x3F80;

  // ---- Q fragments for BOTH phases (loaded once)
  bf16x8 qa0[2], qa1[2];
  {
#pragma unroll
    for (int ph = 0; ph < 2; ++ph) {
      const float* qp = Qb + (size_t)((ph ? rowB : rowA) + c) * D_HEAD + quad * 8;
#pragma unroll
      for (int h = 0; h < 2; ++h) {
        f32x4 a0 = *(const f32x4*)(qp + 32 * h);
        f32x4 a1 = *(const f32x4*)(qp + 32 * h + 4);
#pragma unroll
        for (int j = 0; j < 4; ++j) {
          if (ph) { qa1[h][j] = (short)f2bf(a0[j] * SCALE_L2E);
                    qa1[h][4 + j] = (short)f2bf(a1[j] * SCALE_L2E); }
          else    { qa0[h][j] = (short)f2bf(a0[j] * SCALE_L2E);
                    qa0[h][4 + j] = (short)f2bf(a1[j] * SCALE_L2E); }
        }
      }
    }
  }

  f32x4 oa[4];
  f32x4 lacc;
#pragma unroll
  for (int i = 0; i < 4; ++i) oa[i] = (f32x4){0.f, 0.f, 0.f, 0.f};
  lacc = (f32x4){0.f, 0.f, 0.f, 0.f};

  // ---- flat tile sequence: i=0..32; i<=trA -> (A, kt=i); else (B, kt=i-trA-1)
  auto loadKV = [&](int i, bf16x8 (&kf)[4][2], bf16x8 (&vf)[4][2]) {
    const int kt = (i <= trA) ? i : (i - trA - 1);
    const unsigned short* kp = Kbb + kt * (64 * 64);
    const unsigned short* vp = Vtb + kt * 64;
#pragma unroll
    for (int ci = 0; ci < 4; ++ci)
#pragma unroll
      for (int h = 0; h < 2; ++h) {
        kf[ci][h] = *(const bf16x8*)(kp + kOff[ci][h]);
        vf[ci][h] = *(const bf16x8*)(vp + vOff[ci][h]);
      }
  };

  // softmax + pack + in-register transpose: sc (C layout) -> A frags
  auto smpack = [&](f32x4* sc, bf16x8& p0, bf16x8& p1) {
    unsigned int Wt[4][2];
#pragma unroll
    for (int ci = 0; ci < 4; ++ci) {
#pragma unroll
      for (int r = 0; r < 4; ++r)
        sc[ci][r] = __builtin_amdgcn_exp2f(sc[ci][r]);
      Wt[ci][0] = cvtpk_bf16(sc[ci][0], sc[ci][1]);
      Wt[ci][1] = cvtpk_bf16(sc[ci][2], sc[ci][3]);
    }
    // word (srcQuad sq, block b) -> quad 2(b&1)+(sq>>1); 32-swap + 16-swap
    unsigned int a00 = Wt[0][0], a02 = Wt[1][0]; swap32(a00, a02); swap16(a00, a02);
    unsigned int a01 = Wt[0][1], a03 = Wt[1][1]; swap32(a01, a03); swap16(a01, a03);
    unsigned int a10 = Wt[2][0], a12 = Wt[3][0]; swap32(a10, a12); swap16(a10, a12);
    unsigned int a11 = Wt[2][1], a13 = Wt[3][1]; swap32(a11, a13); swap16(a11, a13);
    p0 = __builtin_bit_cast(bf16x8, (uint4v){a00, a01, a02, a03});
    p1 = __builtin_bit_cast(bf16x8, (uint4v){a10, a11, a12, a13});
  };

  // one 64-col tile: QK^T -> (mask) -> softmax -> PV (+lacc); epilogue at kt==tr
  auto doTile = [&](int kt, int tr, int row0, const bf16x8 (&qaf)[2],
                    bf16x8 (&kf)[4][2], bf16x8 (&vf)[4][2]) {
    __builtin_amdgcn_s_setprio(1);
    f32x4 sc[4];
#pragma unroll
    for (int ci = 0; ci < 4; ++ci) {
      f32x4 acc = (f32x4){-FIXM, -FIXM, -FIXM, -FIXM};
      acc = __builtin_amdgcn_mfma_f32_16x16x32_bf16(kf[ci][0], qaf[0], acc, 0, 0, 0);
      acc = __builtin_amdgcn_mfma_f32_16x16x32_bf16(kf[ci][1], qaf[1], acc, 0, 0, 0);
      sc[ci] = acc;
    }
    if (kt == tr) {                      // diagonal tile mask
      const int grow = row0 + c;
#pragma unroll
      for (int ci = 0; ci < 4; ++ci)
#pragma unroll
        for (int r = 0; r < 4; ++r)
          if (kt * 64 + ci * 16 + quad * 4 + r > grow) sc[ci][r] = -1e30f;
    }
    bf16x8 p0, p1;
    smpack(sc, p0, p1);
#pragma unroll
    for (int ci = 0; ci < 4; ++ci) {
      oa[ci] = __builtin_amdgcn_mfma_f32_16x16x32_bf16(p0, vf[ci][0], oa[ci], 0, 0, 0);
      oa[ci] = __builtin_amdgcn_mfma_f32_16x16x32_bf16(p1, vf[ci][1], oa[ci], 0, 0, 0);
    }
    lacc = __builtin_amdgcn_mfma_f32_16x16x32_bf16(p0, ones, lacc, 0, 0, 0);
    lacc = __builtin_amdgcn_mfma_f32_16x16x32_bf16(p1, ones, lacc, 0, 0, 0);
    __builtin_amdgcn_s_setprio(0);
    if (kt == tr) {                      // phase end: normalize + store + reset
      float inv[4];
#pragma unroll
      for (int r = 0; r < 4; ++r) inv[r] = 1.0f / lacc[r];
#pragma unroll
      for (int ci = 0; ci < 4; ++ci)
#pragma unroll
        for (int r = 0; r < 4; ++r)
          Ob[(size_t)(row0 + quad * 4 + r) * D_HEAD + ci * 16 + c] =
              oa[ci][r] * inv[r];
#pragma unroll
      for (int i2 = 0; i2 < 4; ++i2) oa[i2] = (f32x4){0.f, 0.f, 0.f, 0.f};
      lacc = (f32x4){0.f, 0.f, 0.f, 0.f};
    }
  };

  auto compute = [&](int i, bf16x8 (&kf)[4][2], bf16x8 (&vf)[4][2]) {
    if (i <= trA) doTile(i, trA, rowA, qa0, kf, vf);
    else          doTile(i - trA - 1, trB, rowB, qa1, kf, vf);
  };

  // ---- pipeline reg sets (static parity via unroll-2)
  bf16x8 kfA[4][2], vfA[4][2], kfB[4][2], vfB[4][2];
  loadKV(0, kfA, vfA);
#pragma unroll 1
  for (int i = 0; i < 33; i += 2) {
    if (i + 1 < 33) loadKV(i + 1, kfB, vfB);   // next tile -> B while computing A
    compute(i, kfA, vfA);
    if (i + 1 < 33) {
      if (i + 2 < 33) loadKV(i + 2, kfA, vfA); // tile i+2 -> A while computing B
      compute(i + 1, kfB, vfB);
    }
  }
}

// ---------------- fallback (fp32 inputs direct) if ws too small
__global__ __launch_bounds__(256, 4)
void fa_fb(const float* __restrict__ Qg, const float* __restrict__ Kg,
           const float* __restrict__ Vg, float* __restrict__ Og)
{
  __shared__ __align__(16) unsigned short Ksh[64][72];
  __shared__ __align__(16) unsigned short Vsh[64][72];
  __shared__ __align__(16) unsigned short Psh[4][16][72];
  const int id = blockIdx.x;
  const int bh = id & 31;
  const int p  = id >> 5;
  const int t    = threadIdx.x;
  const int w    = t >> 6;
  const int lane = t & 63;
  const int c    = lane & 15;
  const int quad = lane >> 4;
  const size_t base = (size_t)bh * (S_LEN * D_HEAD);
  const float* __restrict__ Qb = Qg + base;
  const float* __restrict__ Kb = Kg + base;
  const float* __restrict__ Vb = Vg + base;
  float* __restrict__ Ob = Og + base;
  const int wv   = w & 1;
  const int row0 = (w >= 2) ? (S_LEN - 32 * (p + 1) + 16 * wv) : (32 * p + 16 * wv);
  const int ktdiag = row0 >> 6;
  const int ktmax  = (S_LEN - 1 - 32 * p) >> 6;
  bf16x8 qa[2];
  {
    const float* qp = Qb + (size_t)(row0 + c) * D_HEAD + quad * 8;
#pragma unroll
    for (int h = 0; h < 2; ++h) {
      f32x4 a0 = *(const f32x4*)(qp + 32 * h);
      f32x4 a1 = *(const f32x4*)(qp + 32 * h + 4);
#pragma unroll
      for (int j = 0; j < 4; ++j) {
        qa[h][j]     = (short)f2bf(a0[j] * SCALE_L2E);
        qa[h][4 + j] = (short)f2bf(a1[j] * SCALE_L2E);
      }
    }
  }
  f32x4 oa[4];
  float ls[4];
#pragma unroll
  for (int i = 0; i < 4; ++i) {
    oa[i] = (f32x4){0.f, 0.f, 0.f, 0.f};
    ls[i] = 0.f;
  }
  for (int kt = 0; kt <= ktmax; ++kt) {
    __syncthreads();
    {
      const int cp = t & 15;
      const int rg = t >> 4;
      const int col0 = cp * 4;
      const int sw = (cp >> 2) << 3;
#pragma unroll
      for (int i = 0; i < 4; ++i) {
        const int row = i * 16 + rg;
        const size_t goff = (size_t)(kt * 64 + row) * D_HEAD + col0;
        const f32x4 kv = *(const f32x4*)(Kb + goff);
        const f32x4 vv = *(const f32x4*)(Vb + goff);
        const unsigned int k01 = (rnd_bf(kv[1]) & 0xFFFF0000u) | (rnd_bf(kv[0]) >> 16);
        const unsigned int k23 = (rnd_bf(kv[3]) & 0xFFFF0000u) | (rnd_bf(kv[2]) >> 16);
        *(uint2*)&Ksh[row][col0] = make_uint2(k01, k23);
        const int kz = row ^ sw;
#pragma unroll
        for (int e = 0; e < 4; ++e)
          Vsh[col0 + e][kz] = f2bf(vv[e]);
      }
    }
    __syncthreads();
    if (kt <= ktdiag) {
      bf16x8 kf[4][2], vf[4][2];
#pragma unroll
      for (int ci = 0; ci < 4; ++ci) {
        kf[ci][0] = *(const bf16x8*)&Ksh[ci * 16 + c][quad * 8];
        kf[ci][1] = *(const bf16x8*)&Ksh[ci * 16 + c][32 + quad * 8];
        vf[ci][0] = *(const bf16x8*)&Vsh[ci * 16 + c][(quad ^ ci) * 8];
        vf[ci][1] = *(const bf16x8*)&Vsh[ci * 16 + c][32 + ((quad ^ ci) * 8)];
      }
      f32x4 sc[4];
#pragma unroll
      for (int ci = 0; ci < 4; ++ci) {
        f32x4 acc = (f32x4){-FIXM, -FIXM, -FIXM, -FIXM};
        acc = __builtin_amdgcn_mfma_f32_16x16x32_bf16(qa[0], kf[ci][0], acc, 0, 0, 0);
        acc = __builtin_amdgcn_mfma_f32_16x16x32_bf16(qa[1], kf[ci][1], acc, 0, 0, 0);
        sc[ci] = acc;
      }
      if (kt == ktdiag) {
#pragma unroll
        for (int ci = 0; ci < 4; ++ci) {
          const int gcol = kt * 64 + ci * 16 + c;
#pragma unroll
          for (int r = 0; r < 4; ++r)
            if (gcol > row0 + quad * 4 + r) sc[ci][r] = -1e30f;
        }
      }
#pragma unroll
      for (int ci = 0; ci < 4; ++ci)
#pragma unroll
        for (int r = 0; r < 4; ++r)
          sc[ci][r] = __builtin_amdgcn_exp2f(sc[ci][r]);
#pragma unroll
      for (int r = 0; r < 4; ++r)
        ls[r] += (sc[0][r] + sc[1][r]) + (sc[2][r] + sc[3][r]);
#pragma unroll
      for (int ci = 0; ci < 4; ++ci)
#pragma unroll
        for (int r = 0; r < 4; ++r) {
          const int prow = quad * 4 + r;
          Psh[w][prow][(ci * 16 + c) ^ ((prow >> 3) << 3)] = f2bf(sc[ci][r]);
        }
      const int px = (c >> 3) << 3;
      const bf16x8 pa0 = *(const bf16x8*)&Psh[w][c][(quad * 8) ^ px];
      const bf16x8 pa1 = *(const bf16x8*)&Psh[w][c][((32 + quad * 8)) ^ px];
#pragma unroll
      for (int ci = 0; ci < 4; ++ci) {
        oa[ci] = __builtin_amdgcn_mfma_f32_16x16x32_bf16(pa0, vf[ci][0], oa[ci], 0, 0, 0);
        oa[ci] = __builtin_amdgcn_mfma_f32_16x16x32_bf16(pa1, vf[ci][1], oa[ci], 0, 0, 0);
      }
    }
  }
  {
    float inv[4];
#pragma unroll
    for (int r = 0; r < 4; ++r) inv[r] = 1.0f / rowsum16(ls[r]);
#pragma unroll
    for (int ci = 0; ci < 4; ++ci)
#pragma unroll
      for (int r = 0; r < 4; ++r)
        Ob[(size_t)(row0 + quad * 4 + r) * D_HEAD + ci * 16 + c] = oa[ci][r] * inv[r];
  }
}

extern "C" void kernel_launch(void* const* d_in, const int* in_sizes, int n_in,
                              void* d_out, int out_size, void* d_ws, size_t ws_size,
                              hipStream_t stream) {
  (void)in_sizes; (void)n_in; (void)out_size;
  const float* Q = (const float*)d_in[0];
  const float* K = (const float*)d_in[1];
  const float* V = (const float*)d_in[2];
  float* O = (float*)d_out;   // d_in[3] (causal mask) computed analytically
  const size_t NEED = 2ull * 32 * S_LEN * D_HEAD * 2;  // Kb16 + Vt = 16 MB
  if (ws_size >= NEED) {
    unsigned short* Kb = (unsigned short*)d_ws;
    unsigned short* Vt = Kb + (size_t)32 * S_LEN * D_HEAD;
    prep<<<dim3(512), dim3(256), 0, stream>>>(K, V, Kb, Vt);
    fa<<<dim3(512), dim3(256), 0, stream>>>(Q, Kb, Vt, O);
  } else {
    fa_fb<<<dim3(1024), dim3(256), 0, stream>>>(Q, K, V, O);
  }
}

// Round 11
// 131.025 us; speedup vs baseline: 1.6941x; 1.6941x over previous
//
#include <hip/hip_runtime.h>
#include <math.h>

// Causal MHA forward, B=2 H=16 S=2048 D=64, fp32 in/out, bf16 MFMA compute.
// Round 16: restore round-12 fa VERBATIM (proven best, 130.8 us total).
// Round-15 barrier-free/direct-L2 fa regressed 3.3x (scattered 16B fragment
// loads saturate L2 request bandwidth: 254 GB/s, MfmaUtil 5.8) — closes the
// direct-L2 branch for good; K/V fragments must come from LDS.
// One low-risk change: prep at 1024 blocks (4/CU, half work per block, one
// sync pair instead of four) — prep is latency/tail-bound, not BW-bound.

#define S_LEN   2048
#define D_HEAD  64
#define SCALE_L2E 0.18033688011112042f   // (1/sqrt(D)) * log2(e)
#define FIXM    8.0f                     // fixed softmax offset (exponent-safe)

using bf16x8 = __attribute__((ext_vector_type(8))) short;
using f32x4  = __attribute__((ext_vector_type(4))) float;
using uint4v = __attribute__((ext_vector_type(4))) unsigned int;

__device__ __forceinline__ unsigned int rnd_bf(float f) {
  return __float_as_uint(f) + 0x8000u;
}
__device__ __forceinline__ unsigned short f2bf(float f) {
  return (unsigned short)(rnd_bf(f) >> 16);
}

// async global->LDS, 16B per lane; LDS dest = uniform base + lane*16
__device__ __forceinline__ void gl_lds16(const unsigned short* g, unsigned short* l) {
  __builtin_amdgcn_global_load_lds(
      (const __attribute__((address_space(1))) unsigned int*)g,
      (__attribute__((address_space(3))) unsigned int*)l, 16, 0, 0);
}

// pack two f32 -> one dword of 2 x bf16 (lo = first arg)
__device__ __forceinline__ unsigned int cvtpk_bf16(float lo, float hi) {
  unsigned int r;
  asm("v_cvt_pk_bf16_f32 %0, %1, %2" : "=v"(r) : "v"(lo), "v"(hi));
  return r;
}
// a' = [a.lo32, b.lo32]; b' = [a.hi32, b.hi32]
__device__ __forceinline__ void swap32(unsigned int& a, unsigned int& b) {
  asm("v_permlane32_swap_b32 %0, %1" : "+v"(a), "+v"(b));
}
// rows = 16-lane groups: a' = [a.r0, b.r0, a.r2, b.r2]; b' = [a.r1, b.r1, a.r3, b.r3]
__device__ __forceinline__ void swap16(unsigned int& a, unsigned int& b) {
  asm("v_permlane16_swap_b32 %0, %1" : "+v"(a), "+v"(b));
}

// DPP cross-lane 16-wide sum (fa_fb epilogue only)
template <int CTRL>
__device__ __forceinline__ float dppf(float x) {
  return __builtin_bit_cast(float,
      __builtin_amdgcn_update_dpp(0, __builtin_bit_cast(int, x), CTRL, 0xF, 0xF, false));
}
__device__ __forceinline__ float rowsum16(float x) {
  x += dppf<0xB1>(x);
  x += dppf<0x4E>(x);
  x += dppf<0x124>(x);
  x += dppf<0x128>(x);
  return x;
}

// ---------------- pre-pass (1024 blocks): K -> bf16 [bh][s][d];
// ---------------- V -> bf16 transposed [bh][d][s]. 64 rows per block.
__global__ __launch_bounds__(256, 4)
void prep(const float* __restrict__ Kg, const float* __restrict__ Vg,
          unsigned short* __restrict__ Kb, unsigned short* __restrict__ Vt)
{
  __shared__ __align__(16) unsigned short Lt[64][72];
  const int j = blockIdx.x, t = threadIdx.x;
  const int bh = j >> 5, seg = j & 31;          // 64-row segment
  const size_t base = (size_t)bh * (S_LEN * D_HEAD) + (size_t)seg * 64 * D_HEAD;
#pragma unroll
  for (int i = 0; i < 4; ++i) {                 // K convert: 4096 elems/block
    const size_t idx = base + i * 1024 + t * 4;
    const f32x4 v = *(const f32x4*)(Kg + idx);
    uint2 pk;
    pk.x = (rnd_bf(v[1]) & 0xFFFF0000u) | (rnd_bf(v[0]) >> 16);
    pk.y = (rnd_bf(v[3]) & 0xFFFF0000u) | (rnd_bf(v[2]) >> 16);
    *(uint2*)(Kb + idx) = pk;
  }
  // V transpose: rows s0..s0+63 -> Vt[bh*64+d][s0..s0+63]
  const int s0 = seg * 64;
#pragma unroll
  for (int pp = 0; pp < 4; ++pp) {
    const int r = t >> 2;
    const int d0 = (t & 3) * 4 + pp * 16;
    const f32x4 v = *(const f32x4*)(Vg + (size_t)bh * (S_LEN * D_HEAD)
                                       + (size_t)(s0 + r) * D_HEAD + d0);
#pragma unroll
    for (int e = 0; e < 4; ++e) Lt[d0 + e][r] = f2bf(v[e]);
  }
  __syncthreads();
#pragma unroll
  for (int q = 0; q < 2; ++q) {
    const int d = t >> 2, ch = (t & 3) + 4 * q;
    *(uint4*)(Vt + (size_t)(bh * 64 + d) * S_LEN + s0 + ch * 8) =
        *(const uint4*)&Lt[d][ch * 8];
  }
}

// ---------------- main attention: 4 waves x 16 rows, paired tile-rows,
// ---------------- two dovetailed 64-col sub-tiles per barrier interval
__global__ __launch_bounds__(256, 2)
void fa(const float* __restrict__ Qg, const unsigned short* __restrict__ Kb,
        const unsigned short* __restrict__ Vt, float* __restrict__ Og)
{
  __shared__ unsigned short Ks[2][2][64][64];   // [buf][sub] 32 KB
  __shared__ unsigned short Vs[2][2][64][64];   // 32 KB -> 64 KB, 2 blk/CU

  const int id = blockIdx.x;            // 512 blocks
  const int bh = id & 31;               // id%8 == bh%8 -> head-local XCD L2 reuse
  const int pr = id >> 5;               // tile-row pair 0..15

  const int t    = threadIdx.x;         // 0..255
  const int w    = t >> 6;
  const int lane = t & 63;
  const int c    = lane & 15;
  const int quad = lane >> 4;

  const float* __restrict__ Qb = Qg + (size_t)bh * (S_LEN * D_HEAD);
  float* __restrict__ Ob = Og + (size_t)bh * (S_LEN * D_HEAD);

  const int tr0 = pr, tr1 = 31 - pr;

  // ---- loop-invariant swizzled LDS offsets (shorts); same for K and V tiles
  int fOff[4][2];
#pragma unroll
  for (int ci = 0; ci < 4; ++ci)
#pragma unroll
    for (int h = 0; h < 2; ++h)
      fOff[ci][h] = ((ci * 16 + c) << 6) + (((h * 4 + quad) ^ (c & 7)) << 3);

  // ones B-fragment for the row-sum MFMA (bf16 1.0)
  bf16x8 ones;
#pragma unroll
  for (int j = 0; j < 8; ++j) ones[j] = (short)0x3F80;

  // per-wave staging: 2 instrs K + 2 instrs V per 64-col sub-tile
  const int rl = lane >> 3;
  const int jj = (lane & 7) ^ rl;
  auto stage1 = [&](int kt, int buf, int sub) {
#pragma unroll
    for (int n = 0; n < 2; ++n) {
      const int row = w * 16 + n * 8 + rl;
      gl_lds16(Kb + (((size_t)(bh * S_LEN + kt * 64 + row)) << 6) + jj * 8,
               &Ks[buf][sub][w * 16 + n * 8][0]);
      gl_lds16(Vt + (((size_t)(bh * 64 + row)) << 11) + kt * 64 + jj * 8,
               &Vs[buf][sub][w * 16 + n * 8][0]);
    }
  };
  auto stage_pair = [&](int it, int tr, int buf) {
    const int k0 = 2 * it;
    stage1(k0, buf, 0);                  // caller guarantees k0 <= tr
    if (k0 + 1 <= tr) stage1(k0 + 1, buf, 1);
  };

  // softmax + pack + in-register transpose: sc (C layout) -> A frags
  auto smpack = [&](f32x4* sc, bf16x8& p0, bf16x8& p1) {
    unsigned int Wt[4][2];
#pragma unroll
    for (int ci = 0; ci < 4; ++ci) {
#pragma unroll
      for (int r = 0; r < 4; ++r)
        sc[ci][r] = __builtin_amdgcn_exp2f(sc[ci][r]);
      Wt[ci][0] = cvtpk_bf16(sc[ci][0], sc[ci][1]);
      Wt[ci][1] = cvtpk_bf16(sc[ci][2], sc[ci][3]);
    }
    // word (srcQuad sq, block b) -> quad 2(b&1)+(sq>>1); 32-swap + 16-swap
    unsigned int a00 = Wt[0][0], a02 = Wt[1][0]; swap32(a00, a02); swap16(a00, a02);
    unsigned int a01 = Wt[0][1], a03 = Wt[1][1]; swap32(a01, a03); swap16(a01, a03);
    unsigned int a10 = Wt[2][0], a12 = Wt[3][0]; swap32(a10, a12); swap16(a10, a12);
    unsigned int a11 = Wt[2][1], a13 = Wt[3][1]; swap32(a11, a13); swap16(a11, a13);
    p0 = __builtin_bit_cast(bf16x8, (uint4v){a00, a01, a02, a03});
    p1 = __builtin_bit_cast(bf16x8, (uint4v){a10, a11, a12, a13});
  };

  bf16x8 qa[2];
  f32x4 oa[4];
  f32x4 lacc;

  int buf = 0;
  stage_pair(0, tr0, 0);                 // prologue: phase-0 pair 0

#pragma unroll 1
  for (int ph = 0; ph < 2; ++ph) {
    const int tr    = ph ? tr1 : tr0;    // tile-row; diag at kt == tr
    const int row0  = tr * 64 + w * 16;  // this wave's 16 rows
    const int iters = (tr + 2) >> 1;     // ceil((tr+1)/2); sums to 17 over phases

    // ---- Q fragment (B-operand of swapped QK^T), pre-scaled bf16
    {
      const float* qp = Qb + (size_t)(row0 + c) * D_HEAD + quad * 8;
#pragma unroll
      for (int h = 0; h < 2; ++h) {
        f32x4 a0 = *(const f32x4*)(qp + 32 * h);
        f32x4 a1 = *(const f32x4*)(qp + 32 * h + 4);
#pragma unroll
        for (int j = 0; j < 4; ++j) {
          qa[h][j]     = (short)f2bf(a0[j] * SCALE_L2E);
          qa[h][4 + j] = (short)f2bf(a1[j] * SCALE_L2E);
        }
      }
    }
#pragma unroll
    for (int i = 0; i < 4; ++i) oa[i] = (f32x4){0.f, 0.f, 0.f, 0.f};
    lacc = (f32x4){0.f, 0.f, 0.f, 0.f};

#pragma unroll 1
    for (int it = 0; it < iters; ++it) {
      __syncthreads();                   // drains prefetch + prior LDS reads
      // prefetch next pair (or hand off to phase 1's first pair)
      if (it + 1 < iters)  stage_pair(it + 1, tr, buf ^ 1);
      else if (ph == 0)    stage_pair(0, tr1, buf ^ 1);

      const int kt0 = 2 * it, kt1 = kt0 + 1;
      const bool has1 = (kt1 <= tr);     // block-uniform

      // ---- K fragments (both sub-tiles)
      const unsigned short* ks0 = &Ks[buf][0][0][0];
      const unsigned short* ks1 = &Ks[buf][1][0][0];
      bf16x8 kf0[4][2], kf1[4][2];
#pragma unroll
      for (int ci = 0; ci < 4; ++ci)
#pragma unroll
        for (int h = 0; h < 2; ++h)
          kf0[ci][h] = *(const bf16x8*)(ks0 + fOff[ci][h]);
      if (has1)
#pragma unroll
        for (int ci = 0; ci < 4; ++ci)
#pragma unroll
          for (int h = 0; h < 2; ++h)
            kf1[ci][h] = *(const bf16x8*)(ks1 + fOff[ci][h]);

      __builtin_amdgcn_s_setprio(1);
      // ---- QK^T (swapped) for both sub-tiles
      f32x4 sc0[4], sc1[4];
#pragma unroll
      for (int ci = 0; ci < 4; ++ci) {
        f32x4 acc = (f32x4){-FIXM, -FIXM, -FIXM, -FIXM};
        acc = __builtin_amdgcn_mfma_f32_16x16x32_bf16(kf0[ci][0], qa[0], acc, 0, 0, 0);
        acc = __builtin_amdgcn_mfma_f32_16x16x32_bf16(kf0[ci][1], qa[1], acc, 0, 0, 0);
        sc0[ci] = acc;
      }
      if (has1)
#pragma unroll
        for (int ci = 0; ci < 4; ++ci) {
          f32x4 acc = (f32x4){-FIXM, -FIXM, -FIXM, -FIXM};
          acc = __builtin_amdgcn_mfma_f32_16x16x32_bf16(kf1[ci][0], qa[0], acc, 0, 0, 0);
          acc = __builtin_amdgcn_mfma_f32_16x16x32_bf16(kf1[ci][1], qa[1], acc, 0, 0, 0);
          sc1[ci] = acc;
        }

      // ---- V fragments issued now; latency hides under softmax VALU
      const unsigned short* vs0 = &Vs[buf][0][0][0];
      const unsigned short* vs1 = &Vs[buf][1][0][0];
      bf16x8 vf0[4][2], vf1[4][2];
#pragma unroll
      for (int ci = 0; ci < 4; ++ci)
#pragma unroll
        for (int h = 0; h < 2; ++h)
          vf0[ci][h] = *(const bf16x8*)(vs0 + fOff[ci][h]);
      if (has1)
#pragma unroll
        for (int ci = 0; ci < 4; ++ci)
#pragma unroll
          for (int h = 0; h < 2; ++h)
            vf1[ci][h] = *(const bf16x8*)(vs1 + fOff[ci][h]);

      // ---- diagonal masks (block-uniform predicates)
      if (kt0 == tr) {
        const int grow = row0 + c;
#pragma unroll
        for (int ci = 0; ci < 4; ++ci)
#pragma unroll
          for (int r = 0; r < 4; ++r)
            if (kt0 * 64 + ci * 16 + quad * 4 + r > grow) sc0[ci][r] = -1e30f;
      }
      if (has1 && kt1 == tr) {
        const int grow = row0 + c;
#pragma unroll
        for (int ci = 0; ci < 4; ++ci)
#pragma unroll
          for (int r = 0; r < 4; ++r)
            if (kt1 * 64 + ci * 16 + quad * 4 + r > grow) sc1[ci][r] = -1e30f;
      }

      // ---- softmax + pack + transpose (s0 then s1; overlaps QK/PV MFMA)
      bf16x8 paA0, paA1, paB0, paB1;
      smpack(sc0, paA0, paA1);
      if (has1) smpack(sc1, paB0, paB1);

      // ---- PV + row-sum MFMA (lacc layout == oa layout)
#pragma unroll
      for (int ci = 0; ci < 4; ++ci) {
        oa[ci] = __builtin_amdgcn_mfma_f32_16x16x32_bf16(paA0, vf0[ci][0], oa[ci], 0, 0, 0);
        oa[ci] = __builtin_amdgcn_mfma_f32_16x16x32_bf16(paA1, vf0[ci][1], oa[ci], 0, 0, 0);
      }
      lacc = __builtin_amdgcn_mfma_f32_16x16x32_bf16(paA0, ones, lacc, 0, 0, 0);
      lacc = __builtin_amdgcn_mfma_f32_16x16x32_bf16(paA1, ones, lacc, 0, 0, 0);
      if (has1) {
#pragma unroll
        for (int ci = 0; ci < 4; ++ci) {
          oa[ci] = __builtin_amdgcn_mfma_f32_16x16x32_bf16(paB0, vf1[ci][0], oa[ci], 0, 0, 0);
          oa[ci] = __builtin_amdgcn_mfma_f32_16x16x32_bf16(paB1, vf1[ci][1], oa[ci], 0, 0, 0);
        }
        lacc = __builtin_amdgcn_mfma_f32_16x16x32_bf16(paB0, ones, lacc, 0, 0, 0);
        lacc = __builtin_amdgcn_mfma_f32_16x16x32_bf16(paB1, ones, lacc, 0, 0, 0);
      }
      __builtin_amdgcn_s_setprio(0);

      buf ^= 1;
    }

    // ---- epilogue: no cross-lane work needed; lacc[r] = rowsum(q-row quad*4+r)
    {
      float inv[4];
#pragma unroll
      for (int r = 0; r < 4; ++r) inv[r] = 1.0f / lacc[r];
#pragma unroll
      for (int ci = 0; ci < 4; ++ci)
#pragma unroll
        for (int r = 0; r < 4; ++r)
          Ob[(size_t)(row0 + quad * 4 + r) * D_HEAD + ci * 16 + c] =
              oa[ci][r] * inv[r];
    }
  }
}

// ---------------- fallback (fp32 inputs direct) if ws too small
__global__ __launch_bounds__(256, 4)
void fa_fb(const float* __restrict__ Qg, const float* __restrict__ Kg,
           const float* __restrict__ Vg, float* __restrict__ Og)
{
  __shared__ __align__(16) unsigned short Ksh[64][72];
  __shared__ __align__(16) unsigned short Vsh[64][72];
  __shared__ __align__(16) unsigned short Psh[4][16][72];
  const int id = blockIdx.x;
  const int bh = id & 31;
  const int p  = id >> 5;
  const int t    = threadIdx.x;
  const int w    = t >> 6;
  const int lane = t & 63;
  const int c    = lane & 15;
  const int quad = lane >> 4;
  const size_t base = (size_t)bh * (S_LEN * D_HEAD);
  const float* __restrict__ Qb = Qg + base;
  const float* __restrict__ Kb = Kg + base;
  const float* __restrict__ Vb = Vg + base;
  float* __restrict__ Ob = Og + base;
  const int wv   = w & 1;
  const int row0 = (w >= 2) ? (S_LEN - 32 * (p + 1) + 16 * wv) : (32 * p + 16 * wv);
  const int ktdiag = row0 >> 6;
  const int ktmax  = (S_LEN - 1 - 32 * p) >> 6;
  bf16x8 qa[2];
  {
    const float* qp = Qb + (size_t)(row0 + c) * D_HEAD + quad * 8;
#pragma unroll
    for (int h = 0; h < 2; ++h) {
      f32x4 a0 = *(const f32x4*)(qp + 32 * h);
      f32x4 a1 = *(const f32x4*)(qp + 32 * h + 4);
#pragma unroll
      for (int j = 0; j < 4; ++j) {
        qa[h][j]     = (short)f2bf(a0[j] * SCALE_L2E);
        qa[h][4 + j] = (short)f2bf(a1[j] * SCALE_L2E);
      }
    }
  }
  f32x4 oa[4];
  float ls[4];
#pragma unroll
  for (int i = 0; i < 4; ++i) {
    oa[i] = (f32x4){0.f, 0.f, 0.f, 0.f};
    ls[i] = 0.f;
  }
  for (int kt = 0; kt <= ktmax; ++kt) {
    __syncthreads();
    {
      const int cp = t & 15;
      const int rg = t >> 4;
      const int col0 = cp * 4;
      const int sw = (cp >> 2) << 3;
#pragma unroll
      for (int i = 0; i < 4; ++i) {
        const int row = i * 16 + rg;
        const size_t goff = (size_t)(kt * 64 + row) * D_HEAD + col0;
        const f32x4 kv = *(const f32x4*)(Kb + goff);
        const f32x4 vv = *(const f32x4*)(Vb + goff);
        const unsigned int k01 = (rnd_bf(kv[1]) & 0xFFFF0000u) | (rnd_bf(kv[0]) >> 16);
        const unsigned int k23 = (rnd_bf(kv[3]) & 0xFFFF0000u) | (rnd_bf(kv[2]) >> 16);
        *(uint2*)&Ksh[row][col0] = make_uint2(k01, k23);
        const int kz = row ^ sw;
#pragma unroll
        for (int e = 0; e < 4; ++e)
          Vsh[col0 + e][kz] = f2bf(vv[e]);
      }
    }
    __syncthreads();
    if (kt <= ktdiag) {
      bf16x8 kf[4][2], vf[4][2];
#pragma unroll
      for (int ci = 0; ci < 4; ++ci) {
        kf[ci][0] = *(const bf16x8*)&Ksh[ci * 16 + c][quad * 8];
        kf[ci][1] = *(const bf16x8*)&Ksh[ci * 16 + c][32 + quad * 8];
        vf[ci][0] = *(const bf16x8*)&Vsh[ci * 16 + c][(quad ^ ci) * 8];
        vf[ci][1] = *(const bf16x8*)&Vsh[ci * 16 + c][32 + ((quad ^ ci) * 8)];
      }
      f32x4 sc[4];
#pragma unroll
      for (int ci = 0; ci < 4; ++ci) {
        f32x4 acc = (f32x4){-FIXM, -FIXM, -FIXM, -FIXM};
        acc = __builtin_amdgcn_mfma_f32_16x16x32_bf16(qa[0], kf[ci][0], acc, 0, 0, 0);
        acc = __builtin_amdgcn_mfma_f32_16x16x32_bf16(qa[1], kf[ci][1], acc, 0, 0, 0);
        sc[ci] = acc;
      }
      if (kt == ktdiag) {
#pragma unroll
        for (int ci = 0; ci < 4; ++ci) {
          const int gcol = kt * 64 + ci * 16 + c;
#pragma unroll
          for (int r = 0; r < 4; ++r)
            if (gcol > row0 + quad * 4 + r) sc[ci][r] = -1e30f;
        }
      }
#pragma unroll
      for (int ci = 0; ci < 4; ++ci)
#pragma unroll
        for (int r = 0; r < 4; ++r)
          sc[ci][r] = __builtin_amdgcn_exp2f(sc[ci][r]);
#pragma unroll
      for (int r = 0; r < 4; ++r)
        ls[r] += (sc[0][r] + sc[1][r]) + (sc[2][r] + sc[3][r]);
#pragma unroll
      for (int ci = 0; ci < 4; ++ci)
#pragma unroll
        for (int r = 0; r < 4; ++r) {
          const int prow = quad * 4 + r;
          Psh[w][prow][(ci * 16 + c) ^ ((prow >> 3) << 3)] = f2bf(sc[ci][r]);
        }
      const int px = (c >> 3) << 3;
      const bf16x8 pa0 = *(const bf16x8*)&Psh[w][c][(quad * 8) ^ px];
      const bf16x8 pa1 = *(const bf16x8*)&Psh[w][c][((32 + quad * 8)) ^ px];
#pragma unroll
      for (int ci = 0; ci < 4; ++ci) {
        oa[ci] = __builtin_amdgcn_mfma_f32_16x16x32_bf16(pa0, vf[ci][0], oa[ci], 0, 0, 0);
        oa[ci] = __builtin_amdgcn_mfma_f32_16x16x32_bf16(pa1, vf[ci][1], oa[ci], 0, 0, 0);
      }
    }
  }
  {
    float inv[4];
#pragma unroll
    for (int r = 0; r < 4; ++r) inv[r] = 1.0f / rowsum16(ls[r]);
#pragma unroll
    for (int ci = 0; ci < 4; ++ci)
#pragma unroll
      for (int r = 0; r < 4; ++r)
        Ob[(size_t)(row0 + quad * 4 + r) * D_HEAD + ci * 16 + c] = oa[ci][r] * inv[r];
  }
}

extern "C" void kernel_launch(void* const* d_in, const int* in_sizes, int n_in,
                              void* d_out, int out_size, void* d_ws, size_t ws_size,
                              hipStream_t stream) {
  (void)in_sizes; (void)n_in; (void)out_size;
  const float* Q = (const float*)d_in[0];
  const float* K = (const float*)d_in[1];
  const float* V = (const float*)d_in[2];
  float* O = (float*)d_out;   // d_in[3] (causal mask) computed analytically
  const size_t NEED = 2ull * 32 * S_LEN * D_HEAD * 2;  // Kb16 + Vt = 16 MB
  if (ws_size >= NEED) {
    unsigned short* Kb = (unsigned short*)d_ws;
    unsigned short* Vt = Kb + (size_t)32 * S_LEN * D_HEAD;
    prep<<<dim3(1024), dim3(256), 0, stream>>>(K, V, Kb, Vt);
    fa<<<dim3(512), dim3(256), 0, stream>>>(Q, Kb, Vt, O);
  } else {
    fa_fb<<<dim3(1024), dim3(256), 0, stream>>>(Q, K, V, O);
  }
}